// Round 6
// baseline (185.655 us; speedup 1.0000x reference)
//
#include <hip/hip_runtime.h>
#include <math.h>

#define BB 4
#define SS 2048
#define DD 512
#define HH 8
#define HD 64
#define NTOK (BB*SS)
#define EPS 1e-5f
#define NE ((size_t)NTOK * DD)
#define WN ((size_t)DD * DD)
#define LOG2E 1.4426950408889634f

typedef _Float16 half8v __attribute__((ext_vector_type(8)));
typedef _Float16 half4v __attribute__((ext_vector_type(4)));
typedef _Float16 half2v __attribute__((ext_vector_type(2)));
typedef float f32x4 __attribute__((ext_vector_type(4)));
typedef unsigned int u32x2 __attribute__((ext_vector_type(2)));
typedef unsigned int u32x4 __attribute__((ext_vector_type(4)));

__device__ __forceinline__ float fast_exp2(float x) {
#if __has_builtin(__builtin_amdgcn_exp2f)
    return __builtin_amdgcn_exp2f(x);
#else
    return __expf(x * 0.6931471805599453f);
#endif
}

__device__ __forceinline__ half2v pack2(float a, float b) {
    return __builtin_bit_cast(half2v, __builtin_amdgcn_cvt_pkrtz(a, b));
}

__device__ __forceinline__ half4v pack4(float a, float b, float c, float d) {
    half2v lo = pack2(a, b);
    half2v hi = pack2(c, d);
    half4v r; r[0] = lo[0]; r[1] = lo[1]; r[2] = hi[0]; r[3] = hi[1];
    return r;
}

__device__ __forceinline__ unsigned pk2u(float a, float b) {
    return __builtin_bit_cast(unsigned, __builtin_amdgcn_cvt_pkrtz(a, b));
}

// permlane swaps (VALU pipe — NOT the DS pipe like __shfl/ds_bpermute).
// p16sw(x,y): out0 = {x.q0, y.q0, x.q2, y.q2}, out1 = {x.q1, y.q1, x.q3, y.q3}
// p32sw(x,y): out0 = {x.q0, x.q1, y.q0, y.q1}, out1 = {x.q2, x.q3, y.q2, y.q3}
// (q = lane>>4, i.e. 16-lane rows)
__device__ __forceinline__ u32x2 p16sw(unsigned x, unsigned y) {
#if __has_builtin(__builtin_amdgcn_permlane16_swap)
    return __builtin_amdgcn_permlane16_swap(x, y, false, false);
#else
    int odd = (__lane_id() >> 4) & 1;
    u32x2 r;
    r[0] = odd ? __shfl_xor((int)y, 16) : (int)x;
    r[1] = odd ? (int)y : __shfl_xor((int)x, 16);
    return r;
#endif
}
__device__ __forceinline__ u32x2 p32sw(unsigned x, unsigned y) {
#if __has_builtin(__builtin_amdgcn_permlane32_swap)
    return __builtin_amdgcn_permlane32_swap(x, y, false, false);
#else
    int hi = (__lane_id() >> 5) & 1;
    u32x2 r;
    r[0] = hi ? __shfl_xor((int)y, 32) : (int)x;
    r[1] = hi ? (int)y : __shfl_xor((int)x, 32);
    return r;
#endif
}
__device__ __forceinline__ float fbits(unsigned u) {
    return __builtin_bit_cast(float, u);
}
__device__ __forceinline__ unsigned ubits(float f) {
    return __builtin_bit_cast(unsigned, f);
}

__device__ __forceinline__ void gload_lds16(const void* g, void* l) {
    __builtin_amdgcn_global_load_lds(
        (const __attribute__((address_space(1))) unsigned int*)g,
        (__attribute__((address_space(3))) unsigned int*)l, 16, 0, 0);
}

// ---------------- final LayerNorm (residual from f16 v16, x from f16 ao) ---
__global__ __launch_bounds__(256) void ln_kernel(const _Float16* __restrict__ x,
                                                 const _Float16* __restrict__ res,
                                                 const float* __restrict__ gamma,
                                                 const float* __restrict__ beta,
                                                 float* __restrict__ y) {
    int row = blockIdx.x;
    int t = threadIdx.x;
    half2v xv = *(const half2v*)&x[(size_t)row * DD + 2 * t];
    half2v rv = *(const half2v*)&res[(size_t)row * DD + 2 * t];
    float2 v;
    v.x = (float)xv[0] + (float)rv[0];
    v.y = (float)xv[1] + (float)rv[1];
    float s = v.x + v.y;
    float ss = v.x * v.x + v.y * v.y;
    #pragma unroll
    for (int off = 32; off; off >>= 1) {
        s  += __shfl_down(s,  off);
        ss += __shfl_down(ss, off);
    }
    __shared__ float ws0[4], ws1[4];
    int wid = t >> 6, lane = t & 63;
    if (lane == 0) { ws0[wid] = s; ws1[wid] = ss; }
    __syncthreads();
    __shared__ float mu_s, rstd_s;
    if (t == 0) {
        float S0 = ws0[0] + ws0[1] + ws0[2] + ws0[3];
        float S1 = ws1[0] + ws1[1] + ws1[2] + ws1[3];
        float mu = S0 * (1.0f / DD);
        float var = S1 * (1.0f / DD) - mu * mu;
        mu_s = mu;
        rstd_s = rsqrtf(var + EPS);
    }
    __syncthreads();
    float mu = mu_s, rstd = rstd_s;
    float2 g = ((const float2*)gamma)[t];
    float2 bb = ((const float2*)beta)[t];
    float2 o;
    o.x = (v.x - mu) * rstd * g.x + bb.x;
    o.y = (v.y - mu) * rstd * g.y + bb.y;
    ((float2*)(y + (size_t)row * DD))[t] = o;
}

// ---------------- prep: LN(seq_v) -> f16 only + cast q/k + cast W ----------
__global__ __launch_bounds__(256) void prep_kernel(const float* __restrict__ seq_v,
                                                   const float* __restrict__ seq_q,
                                                   const float* __restrict__ seq_k,
                                                   const float* __restrict__ W1,
                                                   const float* __restrict__ W2,
                                                   const float* __restrict__ W3,
                                                   const float* __restrict__ gamma,
                                                   const float* __restrict__ beta,
                                                   _Float16* __restrict__ v16,
                                                   _Float16* __restrict__ qk16,
                                                   _Float16* __restrict__ w16) {
    int bid = blockIdx.x;
    int t = threadIdx.x;
    if (bid < NTOK) {
        int row = bid;
        float2 v = ((const float2*)(seq_v + (size_t)row * DD))[t];
        float s = v.x + v.y;
        float ss = v.x * v.x + v.y * v.y;
        #pragma unroll
        for (int off = 32; off; off >>= 1) {
            s  += __shfl_down(s,  off);
            ss += __shfl_down(ss, off);
        }
        __shared__ float ws0[4], ws1[4];
        int wid = t >> 6, lane = t & 63;
        if (lane == 0) { ws0[wid] = s; ws1[wid] = ss; }
        __syncthreads();
        __shared__ float mu_s, rstd_s;
        if (t == 0) {
            float S0 = ws0[0] + ws0[1] + ws0[2] + ws0[3];
            float S1 = ws1[0] + ws1[1] + ws1[2] + ws1[3];
            float mu = S0 * (1.0f / DD);
            float var = S1 * (1.0f / DD) - mu * mu;
            mu_s = mu;
            rstd_s = rsqrtf(var + EPS);
        }
        __syncthreads();
        float mu = mu_s, rstd = rstd_s;
        float2 g = ((const float2*)gamma)[t];
        float2 bb = ((const float2*)beta)[t];
        float2 o;
        o.x = (v.x - mu) * rstd * g.x + bb.x;
        o.y = (v.y - mu) * rstd * g.y + bb.y;
        *(half2v*)&v16[(size_t)row * DD + 2 * t] = pack2(o.x, o.y);
    } else if (bid < 2 * NTOK) {
        size_t i = ((size_t)(bid - NTOK) * 256 + t) * 4;
        const float* src = (i < NE) ? (seq_q + i) : (seq_k + (i - NE));
        float4 v = *(const float4*)src;
        *(half4v*)(qk16 + i) = pack4(v.x, v.y, v.z, v.w);
    } else {
        size_t i = ((size_t)(bid - 2 * NTOK) * 256 + t) * 4;
        const float* src; float sc;
        if (i < WN)          { src = W1 + i;            sc = LOG2E; }
        else if (i < 2 * WN) { src = W2 + (i - WN);     sc = 1.0f; }
        else                 { src = W3 + (i - 2 * WN); sc = 1.0f; }
        float4 v = *(const float4*)src;
        *(half4v*)(w16 + i) = pack4(v.x * sc, v.y * sc, v.z * sc, v.w * sc);
    }
}

// ---------------- MFMA GEMM: all three projections in one launch ------------
// Double-buffered K-loop (prefetch-after-barrier) + XCD-grouped 1D grid.
#define GBM 128
#define GBN 128
#define GBK 64
__global__ __launch_bounds__(256) void gemm_mfma(const _Float16* __restrict__ Aall,
                                                 const _Float16* __restrict__ Wall,
                                                 _Float16* __restrict__ Call,
                                                 _Float16* __restrict__ vtOut) {
    __shared__ __align__(16) _Float16 smem[2][2 * GBM * GBK];   // 64KB: 2 x (A|W)
    int wg = blockIdx.x;
    int local = wg >> 3;                 // 0..95
    int z = local >> 5;                  // 0..2
    int r5 = local & 31;
    int my = (wg & 7) * 8 + (r5 >> 2);   // 0..63  (m-panel)
    int nx = r5 & 3;                     // 0..3   (n-panel)
    bool isv = (z == 2);
    const _Float16* A = Aall + (size_t)z * NE;
    const _Float16* W = Wall + (size_t)z * WN;
    int t = threadIdx.x, w = t >> 6, lane = t & 63, q = lane >> 4, ln = lane & 15;
    int lrow = lane >> 3, lseg = lane & 7;
    int m0 = my * GBM, n0 = nx * GBN;
    int wm = w & 1, wn = w >> 1;
    f32x4 acc[4][4];
    #pragma unroll
    for (int mt = 0; mt < 4; ++mt)
        #pragma unroll
        for (int nt = 0; nt < 4; ++nt)
            acc[mt][nt] = (f32x4){0.f, 0.f, 0.f, 0.f};

    int gs = lseg ^ lrow;

    auto stage = [&](int k0, int buf) {
        _Float16* Asb = smem[buf];
        _Float16* Wsb = smem[buf] + GBM * GBK;
        #pragma unroll
        for (int p = 0; p < 4; ++p) {
            int rr = w * 32 + p * 8 + lrow;
            gload_lds16(A + (size_t)(m0 + rr) * DD + k0 + gs * 8,
                        Asb + (size_t)(w * 32 + p * 8) * GBK);
            gload_lds16(W + (size_t)(n0 + rr) * DD + k0 + gs * 8,
                        Wsb + (size_t)(w * 32 + p * 8) * GBK);
        }
    };

    stage(0, 0);
    const int NK = DD / GBK;   // 8
    for (int ki = 0; ki < NK; ++ki) {
        int cur = ki & 1;
        __syncthreads();
        if (ki + 1 < NK) stage((ki + 1) * GBK, cur ^ 1);
        _Float16* Asb = smem[cur];
        _Float16* Wsb = smem[cur] + GBM * GBK;
        __builtin_amdgcn_s_setprio(1);
        #pragma unroll
        for (int kk = 0; kk < 2; ++kk) {
            int ch = ((4 * kk + q) ^ (ln & 7)) * 8;
            half8v af[4], wf[4];
            #pragma unroll
            for (int mt = 0; mt < 4; ++mt)
                af[mt] = *(half8v*)&Asb[(wm * 64 + mt * 16 + ln) * GBK + ch];
            #pragma unroll
            for (int nt = 0; nt < 4; ++nt)
                wf[nt] = *(half8v*)&Wsb[(wn * 64 + nt * 16 + ln) * GBK + ch];
            if (!isv) {
                #pragma unroll
                for (int mt = 0; mt < 4; ++mt)
                    #pragma unroll
                    for (int nt = 0; nt < 4; ++nt)
                        acc[mt][nt] = __builtin_amdgcn_mfma_f32_16x16x32_f16(
                            wf[nt], af[mt], acc[mt][nt], 0, 0, 0);  // C^T
            } else {
                #pragma unroll
                for (int mt = 0; mt < 4; ++mt)
                    #pragma unroll
                    for (int nt = 0; nt < 4; ++nt)
                        acc[mt][nt] = __builtin_amdgcn_mfma_f32_16x16x32_f16(
                            af[mt], wf[nt], acc[mt][nt], 0, 0, 0);  // C
            }
        }
        __builtin_amdgcn_s_setprio(0);
    }

    // ---- epilogue: swizzled 128x128 f16 LDS tile -> coalesced 16B stores
    _Float16* esm = &smem[0][0];
    if (!isv) {
        #pragma unroll
        for (int mt = 0; mt < 4; ++mt) {
            int mloc = wm * 64 + mt * 16 + ln;
            #pragma unroll
            for (int nt = 0; nt < 4; ++nt) {
                int nloc = wn * 64 + nt * 16 + q * 4;
                int cs = (nloc >> 3) ^ (mloc & 7);
                char* p = (char*)esm + mloc * 256 + cs * 16 + (nloc & 7) * 2;
                *(half4v*)p = pack4(acc[mt][nt][0], acc[mt][nt][1],
                                    acc[mt][nt][2], acc[mt][nt][3]);
            }
        }
    } else {
        #pragma unroll
        for (int nt = 0; nt < 4; ++nt) {
            int dloc = wn * 64 + nt * 16 + ln;
            #pragma unroll
            for (int mt = 0; mt < 4; ++mt) {
                int sloc = wm * 64 + mt * 16 + q * 4;
                int cs = (sloc >> 3) ^ (dloc & 7);
                char* p = (char*)esm + dloc * 256 + cs * 16 + (sloc & 7) * 2;
                *(half4v*)p = pack4(acc[mt][nt][0], acc[mt][nt][1],
                                    acc[mt][nt][2], acc[mt][nt][3]);
            }
        }
    }
    __syncthreads();
    int bq = m0 >> 11, sbase = m0 & (SS - 1);
    if (!isv) {
        _Float16* C = Call + (size_t)z * NE;
        #pragma unroll
        for (int p = 0; p < 8; ++p) {
            int id = p * 256 + t;
            int rr = id >> 4, c = id & 15;
            half8v vv = *(half8v*)((char*)esm + rr * 256 + ((c ^ (rr & 7)) * 16));
            int n = n0 + c * 8;
            int h = n >> 6, d0 = n & 63;
            *(half8v*)&C[((size_t)(bq * HH + h) * SS + (sbase + rr)) * HD + d0] = vv;
        }
    } else {
        #pragma unroll
        for (int p = 0; p < 8; ++p) {
            int id = p * 256 + t;
            int rr = id >> 4, c = id & 15;
            half8v vv = *(half8v*)((char*)esm + rr * 256 + ((c ^ (rr & 7)) * 16));
            int d = n0 + rr;
            int h = d >> 6, dd = d & 63;
            *(half8v*)&vtOut[((size_t)(bq * HH + h) * HD + dd) * SS + sbase + c * 8] = vv;
        }
    }
}

// ---------------- Flash attention, S^T orientation, double-buffered --------
// Round-6: in-register P redistribution (T12 adapted). Instruction-count
// model: DS pipe was the binding resource (18 b128 + 4 b64 + 2 bpermute
// per wave/iter ~= 250 cyc x 16 waves/CU = ~82% of iter time). The Ps
// LDS round-trip (4 ds_write_b64 + 2 ds_read_b128) is replaced by
// permlane16/32_swap routing on the VALU pipe; shfl_xor max-reduce also
// moved to permlane. DS ops 24 -> 16 per wave/iter; Ps buffer freed.
//
// Layout math: lane (q,ln) holds P^T[j = mt*16 + q*4 + r][i = ln] (r=0..3).
// PV B-frag needs P^T[j = ks*32 + q*8 + e][i = ln] (e=0..7):
//   mt = ks*2 + (q>>1);  source q_s = 2*(q&1) + (e>>2);  r = e&3.
// With a[mt][c] = pkrtz(p[mt][2c], p[mt][2c+1]) and s = p32sw(a0,a1):
//   s0 = {a0@q0,a0@q1,a1@q0,a1@q1}, s1 = {a0@q2,a0@q3,a1@q2,a1@q3}
//   G0 (e0-3) = oddq ? p16sw(s1,s1)[0] : s0
//   G1 (e4-7) = oddq ? s1 : p16sw(s0,s0)[1]
#define AI 128
#define AJ 64
__global__ __launch_bounds__(512, 4) void attn_mfma(const _Float16* __restrict__ qh,
                                                    const _Float16* __restrict__ kh,
                                                    const _Float16* __restrict__ vt,
                                                    _Float16* __restrict__ outp) {
    __shared__ __align__(16) _Float16 Qt[2][AJ * HD];   // 64 j x 64 d (swizzled)
    __shared__ __align__(16) _Float16 Vs[2][HD * AJ];   // 64 d x 64 j (swizzled)
    int t = threadIdx.x, w = t >> 6, lane = t & 63, q = lane >> 4, ln = lane & 15;
    bool oddq = (q & 1) != 0;
    // XCD-aware swizzle: each XCD owns 4 whole (b,h); Q+V streams L2-resident.
    int wg = blockIdx.x;
    int slot = wg >> 3;
    int bh = (wg & 7) * 4 + (slot >> 4);
    int i0 = (slot & 15) * AI;
    int b = bh >> 3, h = bh & 7;
    const _Float16* Kb = kh + (size_t)bh * SS * HD;
    const _Float16* Qb = qh + (size_t)bh * SS * HD;
    const _Float16* Vb = vt + (size_t)bh * HD * SS;

    half8v kf[2];
    #pragma unroll
    for (int kk = 0; kk < 2; ++kk)
        kf[kk] = *(const half8v*)&Kb[(size_t)(i0 + w * 16 + ln) * HD + kk * 32 + q * 8];

    f32x4 oacc[4], lacc;
    float m_run = -3.0e38f;
    lacc = (f32x4){0.f, 0.f, 0.f, 0.f};
    #pragma unroll
    for (int mtd = 0; mtd < 4; ++mtd) oacc[mtd] = (f32x4){0.f, 0.f, 0.f, 0.f};
    half8v ones;
    #pragma unroll
    for (int e = 0; e < 8; ++e) ones[e] = (_Float16)1.0f;
    const f32x4 zf = (f32x4){0.f, 0.f, 0.f, 0.f};

    int sr = t >> 3;          // 0..63 (row)
    int sc = t & 7;           // chunk slot
    int ssw = sc ^ (sr & 7);  // swizzled source chunk

    // prologue: stage tile 0 into buffer 0
    gload_lds16(Qb + (size_t)sr * HD + ssw * 8, &Qt[0][(size_t)w * 512]);
    gload_lds16(Vb + (size_t)sr * SS + ssw * 8, &Vs[0][(size_t)w * 512]);

    const int NITER = SS / AJ;   // 32 (even)

#define ATTN_STEP(JT, CUR, DOPF)                                              \
    {                                                                         \
        __syncthreads();                                                      \
        if (DOPF) {                                                           \
            int j1 = ((JT) + 1) * AJ;                                         \
            gload_lds16(Qb + (size_t)(j1 + sr) * HD + ssw * 8,                \
                        &Qt[(CUR) ^ 1][(size_t)w * 512]);                     \
            gload_lds16(Vb + (size_t)sr * SS + j1 + ssw * 8,                  \
                        &Vs[(CUR) ^ 1][(size_t)w * 512]);                     \
        }                                                                     \
        f32x4 sacc[4];                                                        \
        __builtin_amdgcn_s_setprio(1);                                        \
        _Pragma("unroll")                                                     \
        for (int mt = 0; mt < 4; ++mt) {                                      \
            half8v qf = *(half8v*)&Qt[CUR][(mt * 16 + ln) * HD +              \
                                           (q ^ (ln & 7)) * 8];               \
            sacc[mt] = __builtin_amdgcn_mfma_f32_16x16x32_f16(                \
                qf, kf[0], zf, 0, 0, 0);                                      \
        }                                                                     \
        _Pragma("unroll")                                                     \
        for (int mt = 0; mt < 4; ++mt) {                                      \
            half8v qf = *(half8v*)&Qt[CUR][(mt * 16 + ln) * HD +              \
                                           ((4 + q) ^ (ln & 7)) * 8];         \
            sacc[mt] = __builtin_amdgcn_mfma_f32_16x16x32_f16(                \
                qf, kf[1], sacc[mt], 0, 0, 0);                                \
        }                                                                     \
        __builtin_amdgcn_s_setprio(0);                                        \
        float mx = fmaxf(fmaxf(sacc[0][0], sacc[0][1]),                       \
                         fmaxf(sacc[0][2], sacc[0][3]));                      \
        _Pragma("unroll")                                                     \
        for (int mt = 1; mt < 4; ++mt) {                                      \
            float m2 = fmaxf(fmaxf(sacc[mt][0], sacc[mt][1]),                 \
                             fmaxf(sacc[mt][2], sacc[mt][3]));                \
            mx = fmaxf(mx, m2);                                               \
        }                                                                     \
        {   /* cross-row max via permlane (VALU, no DS ops) */                \
            u32x2 mA = p16sw(ubits(mx), ubits(mx));                           \
            mx = fmaxf(mx, fmaxf(fbits(mA[0]), fbits(mA[1])));                \
            u32x2 mB = p32sw(ubits(mx), ubits(mx));                           \
            mx = fmaxf(mx, fmaxf(fbits(mB[0]), fbits(mB[1])));                \
        }                                                                     \
        if (__any(mx > m_run + 7.0f)) {                                       \
            float mn = fmaxf(m_run, mx);                                      \
            float a = fast_exp2(m_run - mn);                                  \
            lacc *= a;                                                        \
            _Pragma("unroll")                                                 \
            for (int mtd = 0; mtd < 4; ++mtd) oacc[mtd] *= a;                 \
            m_run = mn;                                                       \
        }                                                                     \
        unsigned pk[4][2];                                                    \
        _Pragma("unroll")                                                     \
        for (int mt = 0; mt < 4; ++mt) {                                      \
            float p0 = fast_exp2(sacc[mt][0] - m_run);                        \
            float p1 = fast_exp2(sacc[mt][1] - m_run);                        \
            float p2 = fast_exp2(sacc[mt][2] - m_run);                        \
            float p3 = fast_exp2(sacc[mt][3] - m_run);                        \
            pk[mt][0] = pk2u(p0, p1);                                         \
            pk[mt][1] = pk2u(p2, p3);                                         \
        }                                                                     \
        __builtin_amdgcn_s_setprio(1);                                        \
        _Pragma("unroll")                                                     \
        for (int ks = 0; ks < 2; ++ks) {                                      \
            u32x2 s0p = p32sw(pk[2 * ks][0], pk[2 * ks + 1][0]);              \
            u32x2 s1p = p32sw(pk[2 * ks][1], pk[2 * ks + 1][1]);              \
            u32x2 t0p = p16sw(s0p[1], s0p[1]);                                \
            u32x2 u0p = p16sw(s0p[0], s0p[0]);                                \
            u32x2 t1p = p16sw(s1p[1], s1p[1]);                                \
            u32x2 u1p = p16sw(s1p[0], s1p[0]);                                \
            u32x4 F;                                                          \
            F[0] = oddq ? t0p[0] : s0p[0];                                    \
            F[1] = oddq ? t1p[0] : s1p[0];                                    \
            F[2] = oddq ? s0p[1] : u0p[1];                                    \
            F[3] = oddq ? s1p[1] : u1p[1];                                    \
            half8v pf = __builtin_bit_cast(half8v, F);                        \
            int pos = ((ks * 4 + q) ^ (ln & 7)) * 8;                          \
            lacc = __builtin_amdgcn_mfma_f32_16x16x32_f16(                    \
                ones, pf, lacc, 0, 0, 0);                                     \
            _Pragma("unroll")                                                 \
            for (int mtd = 0; mtd < 4; ++mtd) {                               \
                half8v vf = *(half8v*)&Vs[CUR][(size_t)(mtd * 16 + ln) * AJ + \
                                               pos];                          \
                oacc[mtd] = __builtin_amdgcn_mfma_f32_16x16x32_f16(           \
                    vf, pf, oacc[mtd], 0, 0, 0);                              \
            }                                                                 \
        }                                                                     \
        __builtin_amdgcn_s_setprio(0);                                        \
    }

    for (int jtp = 0; jtp < NITER / 2; ++jtp) {
        int jt0 = 2 * jtp;
        ATTN_STEP(jt0, 0, true);
        ATTN_STEP(jt0 + 1, 1, (jtp + 1 < NITER / 2));
    }
#undef ATTN_STEP

    // ---- epilogue: O[i][d] = O^T[d][i] / l  (f16 output) ----
    float inv = 1.0f / lacc[0];
    int i = i0 + w * 16 + ln;
    #pragma unroll
    for (int mtd = 0; mtd < 4; ++mtd) {
        half4v o = pack4(oacc[mtd][0] * inv, oacc[mtd][1] * inv,
                         oacc[mtd][2] * inv, oacc[mtd][3] * inv);
        *(half4v*)&outp[(size_t)(b * SS + i) * DD + h * HD + mtd * 16 + q * 4] = o;
    }
}

extern "C" void kernel_launch(void* const* d_in, const int* in_sizes, int n_in,
                              void* d_out, int out_size, void* d_ws, size_t ws_size,
                              hipStream_t stream) {
    const float* seq_k = (const float*)d_in[0];
    const float* seq_q = (const float*)d_in[1];
    const float* seq_v = (const float*)d_in[2];
    const float* W1    = (const float*)d_in[3];
    const float* W2    = (const float*)d_in[4];
    const float* W3    = (const float*)d_in[5];
    const float* gamma = (const float*)d_in[6];
    const float* beta  = (const float*)d_in[7];
    float* out = (float*)d_out;

    const size_t MB = 1024 * 1024;
    char* w8 = (char*)d_ws;
    _Float16* ao   = (_Float16*)w8;                 // [0,8)  f16 attn out
    _Float16* a16  = (_Float16*)(w8 + 16 * MB);     // q16,k16,v16 [16,40)
    _Float16* w16  = (_Float16*)(w8 + 40 * MB);     // [40,42)
    _Float16* qh   = (_Float16*)(w8 + 48 * MB);     // [48,56)
    _Float16* vt   = (_Float16*)(w8 + 64 * MB);     // [64,72)

    _Float16* q16 = a16;                // q,k contiguous for fused cast
    _Float16* v16 = a16 + 2 * NE;       // [32,40) — residual, live until ln
    _Float16* kh  = qh + NE;

    // 1. fused prep: LN(seq_v)->f16 + cast q/k + cast W (W1 pre-scaled log2e)
    hipLaunchKernelGGL(prep_kernel, dim3(2 * NTOK + 768), dim3(256), 0, stream,
                       seq_v, seq_q, seq_k, W1, W2, W3, gamma, beta,
                       v16, q16, w16);
    // 2. projections (double-buffered, XCD-grouped 1D grid)
    hipLaunchKernelGGL(gemm_mfma, dim3((DD / GBN) * (NTOK / GBM) * 3), dim3(256), 0, stream,
                       a16, w16, qh, vt);
    // 3. flash attention (double-buffered, XCD-swizzled, in-reg P routing)
    hipLaunchKernelGGL(attn_mfma, dim3((SS / AI) * BB * HH), dim3(512), 0, stream,
                       qh, kh, vt, ao);
    // 4. residual + final LN (f16 inputs)
    hipLaunchKernelGGL(ln_kernel, dim3(NTOK), dim3(256), 0, stream,
                       ao, v16, gamma, beta, out);
}